// Round 13
// baseline (102.939 us; speedup 1.0000x reference)
//
#include <hip/hip_runtime.h>
#include <hip/hip_bf16.h>

typedef __attribute__((ext_vector_type(4))) float  f32x4;
typedef __attribute__((ext_vector_type(8))) short  s16x8;

#define D_MODEL 2048
#define NATOMS  64
#define RANK    6
#define NLAYERS 16
#define NAR     384
#define M_TOTAL 16384

#define ASZ  (64*72)     /* shorts: A buffer (+8 pad) */
#define WSZ1 (192*64)    /* shorts: gemm1 W buffer (linear, gload_lds) */

static __device__ __forceinline__ unsigned short f2bf(float x){
    union { float f; unsigned u; } v; v.f = x;
    unsigned r = (v.u + 0x7FFF + ((v.u >> 16) & 1)) >> 16;
    return (unsigned short)r;
}

static __device__ __forceinline__ void gload_lds16(const void* g, void* l) {
    __builtin_amdgcn_global_load_lds(
        (const __attribute__((address_space(1))) unsigned int*)g,
        (__attribute__((address_space(3))) unsigned int*)l, 16, 0, 0);
}

static __device__ __forceinline__ s16x8 cvt8(f32x4 lo, f32x4 hi) {
    union { s16x8 v; unsigned short s[8]; } u;
    u.s[0] = f2bf(lo.x); u.s[1] = f2bf(lo.y); u.s[2] = f2bf(lo.z); u.s[3] = f2bf(lo.w);
    u.s[4] = f2bf(hi.x); u.s[5] = f2bf(hi.y); u.s[6] = f2bf(hi.z); u.s[7] = f2bf(hi.w);
    return u.v;
}

// ---------------------------------------------------------------------------
// Prep: gather layer slice, cast to bf16, lay out K-contiguous.
//   WbfT[n][d]  (n = a*6+r)   from A[a, l, d, r]
//   BbfT[p][n]                from B[a, l, r, p]
// ---------------------------------------------------------------------------
__global__ void prep_kernel(const float* __restrict__ A,
                            const float* __restrict__ B,
                            const int*   __restrict__ layer_idx,
                            unsigned short* __restrict__ WbfT,
                            unsigned short* __restrict__ BbfT)
{
    const int l = layer_idx[0];
    int idx = blockIdx.x * 256 + threadIdx.x;
    const int total = NAR * D_MODEL;   // 786432
    if (idx < total) {
        int n = idx / D_MODEL, d = idx % D_MODEL;
        int a = n / RANK, r = n % RANK;
        float v = A[((size_t)(a*NLAYERS + l) * D_MODEL + d) * RANK + r];
        WbfT[idx] = f2bf(v);
    } else {
        idx -= total;
        int p = idx / NAR, n = idx % NAR;
        int a = n / RANK, r = n % RANK;
        float v = B[((size_t)(a*NLAYERS + l) * RANK + r) * D_MODEL + p];
        BbfT[idx] = f2bf(v);
    }
}

// ---------------------------------------------------------------------------
// GEMM1: P[m][n] = f2bf( scale[b, n/6] * sum_d hidden[m][d] * WbfT[n][d] )
//   BM=64, BN=192 -> 512 blocks = 2 INDEPENDENT blocks/CU (the MLP lever).
//   256 threads = 4 waves (2x2): wave = rows wr*32, cols wc*96, acc[2][6].
//   W total through L2 unchanged (512 x 0.75 MB = 384 MB); hidden read 2x
//   but L3-resident.  Pipeline: W(t+1) gload_lds dbuf (XOR-preswizzled
//   source) + A(t+2) reg ping-pong; barrier = vmcnt(4) (A stays in flight).
// ---------------------------------------------------------------------------
__global__ __launch_bounds__(256, 2) void gemm1(
    const float*          __restrict__ hidden,  // [16384][2048] fp32
    const float*          __restrict__ scales,  // [4][64]
    const unsigned short* __restrict__ WbfT,    // [384][2048] bf16
    unsigned short*       __restrict__ P)       // [16384][384] bf16
{
    __shared__ __align__(16) unsigned short Af[2*ASZ];    // 18432 B
    __shared__ __align__(16) unsigned short Wf[2*WSZ1];   // 49152 B

    const int m0   = blockIdx.x * 64;
    const int n0   = blockIdx.y * 192;
    const int tid  = threadIdx.x;
    const int lane = tid & 63;
    const int w    = tid >> 6;          // 0..3
    const int wr   = w >> 1, wc = w & 1;
    const int kq   = lane >> 4;         // 0..3

    // A staging: thread owns rows rA and rA+32, floats [c8A*8, +8)
    const int rA  = tid >> 3;           // 0..31
    const int c8A = tid & 7;            // 0..7
    const float* srcA = hidden + (size_t)(m0 + rA) * D_MODEL + c8A * 8;

    // W staging: 24 gload_lds of 1KB; wave w does insts i = w*6+j.
    // inst i, lane l -> LDS row r = i*8+(l>>3) (0..191), chunk c = l&7;
    // source pre-swizzled: LDS chunk c holds global chunk c^(r&7).
    const unsigned short* srcW[6];
    int ldsW[6];
    #pragma unroll
    for (int j = 0; j < 6; ++j) {
        int i = w * 6 + j;
        int r = i * 8 + (lane >> 3);
        int c = (lane & 7) ^ (r & 7);
        srcW[j] = WbfT + (size_t)(n0 + r) * D_MODEL + c * 8;
        ldsW[j] = i * 512;   // shorts
    }

    f32x4 acc[2][6] = {};
    f32x4 ga[4], gb[4];

    // ---- prologue ----
    // issue A(0), W(0), A(1); cvt A(0); drain W(0) keeping A(1) in flight
    ga[0] = *reinterpret_cast<const f32x4*>(srcA);
    ga[1] = *reinterpret_cast<const f32x4*>(srcA + 4);
    ga[2] = *reinterpret_cast<const f32x4*>(srcA + 32 * D_MODEL);
    ga[3] = *reinterpret_cast<const f32x4*>(srcA + 32 * D_MODEL + 4);
    srcA += 64;
    #pragma unroll
    for (int j = 0; j < 6; ++j) { gload_lds16(srcW[j], &Wf[ldsW[j]]); srcW[j] += 64; }
    __builtin_amdgcn_sched_barrier(0);
    gb[0] = *reinterpret_cast<const f32x4*>(srcA);
    gb[1] = *reinterpret_cast<const f32x4*>(srcA + 4);
    gb[2] = *reinterpret_cast<const f32x4*>(srcA + 32 * D_MODEL);
    gb[3] = *reinterpret_cast<const f32x4*>(srcA + 32 * D_MODEL + 4);
    srcA += 64;
    *reinterpret_cast<s16x8*>(&Af[rA * 72 + c8A * 8])        = cvt8(ga[0], ga[1]);
    *reinterpret_cast<s16x8*>(&Af[(rA + 32) * 72 + c8A * 8]) = cvt8(ga[2], ga[3]);
    asm volatile("s_waitcnt vmcnt(4) lgkmcnt(0)" ::: "memory");  // W(0) done, A(1) in flight
    __builtin_amdgcn_s_barrier();

    // ---- main loop ----
    auto body = [&](int t, f32x4 (&gI)[4], f32x4 (&gC)[4]) {
        const int buf = t & 1;
        if (t < 31) {
            #pragma unroll
            for (int j = 0; j < 6; ++j) {
                gload_lds16(srcW[j], &Wf[(buf ^ 1) * WSZ1 + ldsW[j]]);
                srcW[j] += 64;
            }
        }
        __builtin_amdgcn_sched_barrier(0);   // pin: W gloads before A loads
        if (t < 30) {
            gI[0] = *reinterpret_cast<const f32x4*>(srcA);
            gI[1] = *reinterpret_cast<const f32x4*>(srcA + 4);
            gI[2] = *reinterpret_cast<const f32x4*>(srcA + 32 * D_MODEL);
            gI[3] = *reinterpret_cast<const f32x4*>(srcA + 32 * D_MODEL + 4);
            srcA += 64;
        }
        const unsigned short* Ar = &Af[buf * ASZ];
        const unsigned short* Wr = &Wf[buf * WSZ1];
        #pragma unroll
        for (int kk = 0; kk < 2; ++kk) {
            const int kch = kk * 4 + kq;
            s16x8 bfr[6], afr[2];
            #pragma unroll
            for (int ni = 0; ni < 6; ++ni) {
                int br = wc * 96 + ni * 16 + (lane & 15);
                bfr[ni] = *reinterpret_cast<const s16x8*>(
                    &Wr[br * 64 + ((kch ^ (br & 7)) << 3)]);
            }
            #pragma unroll
            for (int mi = 0; mi < 2; ++mi) {
                int ar = wr * 32 + mi * 16 + (lane & 15);
                afr[mi] = *reinterpret_cast<const s16x8*>(
                    &Ar[ar * 72 + kk * 32 + kq * 8]);
            }
            #pragma unroll
            for (int mi = 0; mi < 2; ++mi)
                #pragma unroll
                for (int ni = 0; ni < 6; ++ni)
                    acc[mi][ni] = __builtin_amdgcn_mfma_f32_16x16x32_bf16(
                        afr[mi], bfr[ni], acc[mi][ni], 0, 0, 0);
        }
        if (t < 31) {
            *reinterpret_cast<s16x8*>(&Af[(buf ^ 1) * ASZ + rA * 72 + c8A * 8])
                = cvt8(gC[0], gC[1]);
            *reinterpret_cast<s16x8*>(&Af[(buf ^ 1) * ASZ + (rA + 32) * 72 + c8A * 8])
                = cvt8(gC[2], gC[3]);
            if (t == 30) asm volatile("s_waitcnt vmcnt(0) lgkmcnt(0)" ::: "memory");
            else         asm volatile("s_waitcnt vmcnt(4) lgkmcnt(0)" ::: "memory");
            __builtin_amdgcn_s_barrier();
        }
    };
    for (int tt = 0; tt < 32; tt += 2) {
        body(tt,     ga, gb);
        body(tt + 1, gb, ga);
    }

    // ---- epilogue: scale by atom_scales[b, n/6], store bf16 ----
    const int b    = m0 >> 12;
    const int row0 = m0 + wr * 32;
    const int col0 = n0 + wc * 96;
    #pragma unroll
    for (int ni = 0; ni < 6; ++ni) {
        int col  = col0 + ni * 16 + (lane & 15);
        float sc = scales[b * NATOMS + col / RANK];
        #pragma unroll
        for (int mi = 0; mi < 2; ++mi) {
            #pragma unroll
            for (int r = 0; r < 4; ++r) {
                int row = row0 + mi * 16 + kq * 4 + r;
                P[(size_t)row * NAR + col] = f2bf(acc[mi][ni][r] * sc);
            }
        }
    }
}

// ---------------------------------------------------------------------------
// GEMM2: out[m][p] = sum_n P[m][n] * BbfT[p][n]
//   Verbatim proven 23 µs kernel (2048 blocks = 8/CU, HBM floor).
// ---------------------------------------------------------------------------
__global__ __launch_bounds__(256, 2) void gemm2(
    const unsigned short* __restrict__ P,     // [16384][384] bf16
    const unsigned short* __restrict__ BbfT,  // [2048][384] bf16
    float*                __restrict__ out)   // [16384][2048] fp32
{
    __shared__ unsigned short Pt[128][72];
    __shared__ unsigned short Bt[128][72];

    const int m0   = blockIdx.x * 128;
    const int p0   = blockIdx.y * 128;
    const int tid  = threadIdx.x;
    const int lane = tid & 63;
    const int wave = tid >> 6;
    const int wr   = wave >> 1, wc = wave & 1;

    f32x4 acc[4][4] = {};

    for (int k0 = 0; k0 < NAR; k0 += 64) {
        #pragma unroll
        for (int pass = 0; pass < 4; ++pass) {
            int c   = tid + pass * 256;
            int row = c >> 3, c8 = c & 7;
            s16x8 v = *reinterpret_cast<const s16x8*>(
                &P[(size_t)(m0 + row) * NAR + k0 + c8 * 8]);
            *reinterpret_cast<s16x8*>(&Pt[row][c8 * 8]) = v;
        }
        #pragma unroll
        for (int pass = 0; pass < 4; ++pass) {
            int c   = tid + pass * 256;
            int row = c >> 3, c8 = c & 7;
            s16x8 v = *reinterpret_cast<const s16x8*>(
                &BbfT[(size_t)(p0 + row) * NAR + k0 + c8 * 8]);
            *reinterpret_cast<s16x8*>(&Bt[row][c8 * 8]) = v;
        }
        __syncthreads();

        #pragma unroll
        for (int kk = 0; kk < 64; kk += 32) {
            const int krow = kk + (lane >> 4) * 8;
            s16x8 a_frag[4], b_frag[4];
            #pragma unroll
            for (int mi = 0; mi < 4; ++mi)
                a_frag[mi] = *reinterpret_cast<const s16x8*>(
                    &Pt[wr * 64 + mi * 16 + (lane & 15)][krow]);
            #pragma unroll
            for (int ni = 0; ni < 4; ++ni)
                b_frag[ni] = *reinterpret_cast<const s16x8*>(
                    &Bt[wc * 64 + ni * 16 + (lane & 15)][krow]);
            #pragma unroll
            for (int mi = 0; mi < 4; ++mi)
                #pragma unroll
                for (int ni = 0; ni < 4; ++ni)
                    acc[mi][ni] = __builtin_amdgcn_mfma_f32_16x16x32_bf16(
                        a_frag[mi], b_frag[ni], acc[mi][ni], 0, 0, 0);
        }
        __syncthreads();
    }

    const int row0 = m0 + wr * 64;
    const int col0 = p0 + wc * 64;
    #pragma unroll
    for (int mi = 0; mi < 4; ++mi) {
        #pragma unroll
        for (int ni = 0; ni < 4; ++ni) {
            int col = col0 + ni * 16 + (lane & 15);
            #pragma unroll
            for (int r = 0; r < 4; ++r) {
                int row = row0 + mi * 16 + (lane >> 4) * 4 + r;
                out[(size_t)row * D_MODEL + col] = acc[mi][ni][r];
            }
        }
    }
}

extern "C" void kernel_launch(void* const* d_in, const int* in_sizes, int n_in,
                              void* d_out, int out_size, void* d_ws, size_t ws_size,
                              hipStream_t stream)
{
    const float* hidden    = (const float*)d_in[0];
    const float* scales    = (const float*)d_in[1];
    const float* A         = (const float*)d_in[2];
    const float* B         = (const float*)d_in[3];
    const int*   layer_idx = (const int*)d_in[4];
    float* out = (float*)d_out;

    unsigned short* WbfT = (unsigned short*)d_ws;            // [384][2048]
    unsigned short* BbfT = WbfT + (size_t)NAR * D_MODEL;     // [2048][384]
    unsigned short* P    = BbfT + (size_t)D_MODEL * NAR;     // [16384][384]

    prep_kernel<<<(2 * NAR * D_MODEL) / 256, 256, 0, stream>>>(A, B, layer_idx, WbfT, BbfT);
    gemm1<<<dim3(M_TOTAL / 64, NAR / 192), 256, 0, stream>>>(hidden, scales, WbfT, P);
    gemm2<<<dim3(M_TOTAL / 128, D_MODEL / 128), 256, 0, stream>>>(P, BbfT, out);
}

// Round 14
// 95.151 us; speedup vs baseline: 1.0818x; 1.0818x over previous
//
#include <hip/hip_runtime.h>
#include <hip/hip_bf16.h>

typedef __attribute__((ext_vector_type(4))) float  f32x4;
typedef __attribute__((ext_vector_type(8))) short  s16x8;

#define D_MODEL 2048
#define NATOMS  64
#define RANK    6
#define NLAYERS 16
#define NAR     384
#define M_TOTAL 16384

#define ASZ  (64*72)    /* shorts: A buffer (+8 pad) */
#define WSZ  (384*64)   /* shorts: W buffer (linear, gload_lds) */
#define PSTR 392        /* P_lds row stride in shorts */
#define BSZ  (64*384)   /* shorts: one Bt buffer (linear, gload_lds) */

static __device__ __forceinline__ unsigned short f2bf(float x){
    union { float f; unsigned u; } v; v.f = x;
    unsigned r = (v.u + 0x7FFF + ((v.u >> 16) & 1)) >> 16;
    return (unsigned short)r;
}

static __device__ __forceinline__ void gload_lds16(const void* g, void* l) {
    __builtin_amdgcn_global_load_lds(
        (const __attribute__((address_space(1))) unsigned int*)g,
        (__attribute__((address_space(3))) unsigned int*)l, 16, 0, 0);
}

static __device__ __forceinline__ s16x8 cvt8(f32x4 lo, f32x4 hi) {
    union { s16x8 v; unsigned short s[8]; } u;
    u.s[0] = f2bf(lo.x); u.s[1] = f2bf(lo.y); u.s[2] = f2bf(lo.z); u.s[3] = f2bf(lo.w);
    u.s[4] = f2bf(hi.x); u.s[5] = f2bf(hi.y); u.s[6] = f2bf(hi.z); u.s[7] = f2bf(hi.w);
    return u.v;
}

// ---------------------------------------------------------------------------
// Prep: gather layer slice, cast to bf16, lay out K-contiguous.
//   WbfT[n][d]  (n = a*6+r)   from A[a, l, d, r]
//   BbfT[p][n]                from B[a, l, r, p]
// ---------------------------------------------------------------------------
__global__ void prep_kernel(const float* __restrict__ A,
                            const float* __restrict__ B,
                            const int*   __restrict__ layer_idx,
                            unsigned short* __restrict__ WbfT,
                            unsigned short* __restrict__ BbfT)
{
    const int l = layer_idx[0];
    int idx = blockIdx.x * 256 + threadIdx.x;
    const int total = NAR * D_MODEL;   // 786432
    if (idx < total) {
        int n = idx / D_MODEL, d = idx % D_MODEL;
        int a = n / RANK, r = n % RANK;
        float v = A[((size_t)(a*NLAYERS + l) * D_MODEL + d) * RANK + r];
        WbfT[idx] = f2bf(v);
    } else {
        idx -= total;
        int p = idx / NAR, n = idx % NAR;
        int a = n / RANK, r = n % RANK;
        float v = B[((size_t)(a*NLAYERS + l) * RANK + r) * D_MODEL + p];
        BbfT[idx] = f2bf(v);
    }
}

// ---------------------------------------------------------------------------
// Fused LoRA (256 blocks = 1/CU, 512 threads = 8 waves).
//   Phase 1 (verbatim R10): P[64][384] = scale*(hidden @ W^T) in regs;
//            W dbuf gload_lds + XOR swizzle; A reg-staged; counted vmcnt(2).
//   Phase 2 (reworked): out[64][2048] = P @ B^T with 4-row x 2-col wave
//            partition: each wave owns 16 P-rows -> pf[12] = 48 VGPRs,
//            small enough for the allocator to keep REGISTER-RESIDENT
//            across all 32 tiles (kills the 6 MB/block LDS re-read that
//            bound R10's phase 2).  B staged per 64-col tile via gload_lds
//            dbuf (XOR-preswizzled source); tile barrier = vmcnt(8).
// ---------------------------------------------------------------------------
__global__ __launch_bounds__(512, 1) void fused_lora(
    const float*          __restrict__ hidden,  // [16384][2048] fp32
    const float*          __restrict__ scales,  // [4][64]
    const unsigned short* __restrict__ WbfT,    // [384][2048] bf16
    const unsigned short* __restrict__ BbfT,    // [2048][384] bf16
    float*                __restrict__ out)     // [16384][2048] fp32
{
    __shared__ __align__(16) char smem[148480];
    unsigned short* Af = (unsigned short*)smem;            // 2*ASZ  (18432 B)
    unsigned short* Wf = (unsigned short*)(smem + 18432);  // 2*WSZ  (98304 B)
    unsigned short* Pl = (unsigned short*)smem;            // 64x392 (50176 B)
    unsigned short* Bt = (unsigned short*)(smem + 50176);  // 2*BSZ  (98304 B)

    const int m0   = blockIdx.x * 64;
    const int tid  = threadIdx.x;
    const int lane = tid & 63;
    const int w    = tid >> 6;          // 0..7
    const int wr   = w >> 2, wc = w & 3;   // phase1: rows wr*32, cols wc*96
    const int kq   = lane >> 4;         // 0..3

    // ---- phase 1 setup ----
    const int rowA = tid >> 3;          // 0..63
    const int c8A  = tid & 7;           // 0..7
    const float* srcA = hidden + (size_t)(m0 + rowA) * D_MODEL + c8A * 8;

    // W staging: 48 gload_lds of 1KB; wave w does insts i = w*6+j.
    const unsigned short* srcW[6];
    int ldsW[6];
    #pragma unroll
    for (int j = 0; j < 6; ++j) {
        int i = w * 6 + j;
        int r = i * 8 + (lane >> 3);
        int c = (lane & 7) ^ (r & 7);
        srcW[j] = WbfT + (size_t)r * D_MODEL + c * 8;
        ldsW[j] = i * 512;   // shorts
    }

    f32x4 acc[2][6] = {};
    f32x4 ga[2], gb[2];

    // ---- phase 1 prologue ----
    ga[0] = *reinterpret_cast<const f32x4*>(srcA);
    ga[1] = *reinterpret_cast<const f32x4*>(srcA + 4);
    srcA += 64;
    {
        s16x8 s = cvt8(ga[0], ga[1]);
        *reinterpret_cast<s16x8*>(&Af[rowA * 72 + c8A * 8]) = s;
    }
    #pragma unroll
    for (int j = 0; j < 6; ++j) { gload_lds16(srcW[j], &Wf[ldsW[j]]); srcW[j] += 64; }
    __builtin_amdgcn_sched_barrier(0);
    gb[0] = *reinterpret_cast<const f32x4*>(srcA);          // A(1)
    gb[1] = *reinterpret_cast<const f32x4*>(srcA + 4);
    srcA += 64;
    asm volatile("s_waitcnt vmcnt(2) lgkmcnt(0)" ::: "memory");  // W(0) done, A(1) in flight
    __builtin_amdgcn_s_barrier();

    // ---- phase 1 main loop ----
    auto body = [&](int t, f32x4 (&gI)[2], f32x4 (&gC)[2]) {
        const int buf = t & 1;
        if (t < 31) {
            #pragma unroll
            for (int j = 0; j < 6; ++j) {
                gload_lds16(srcW[j], &Wf[(buf ^ 1) * WSZ + ldsW[j]]);
                srcW[j] += 64;
            }
        }
        __builtin_amdgcn_sched_barrier(0);   // pin: W gloads before A loads
        if (t < 30) {
            gI[0] = *reinterpret_cast<const f32x4*>(srcA);
            gI[1] = *reinterpret_cast<const f32x4*>(srcA + 4);
            srcA += 64;
        }
        const unsigned short* Ar = &Af[buf * ASZ];
        const unsigned short* Wr = &Wf[buf * WSZ];
        #pragma unroll
        for (int kk = 0; kk < 2; ++kk) {
            const int kch = kk * 4 + kq;
            s16x8 bfr[6], afr[2];
            #pragma unroll
            for (int ni = 0; ni < 6; ++ni) {
                int br = wc * 96 + ni * 16 + (lane & 15);
                bfr[ni] = *reinterpret_cast<const s16x8*>(
                    &Wr[br * 64 + ((kch ^ (br & 7)) << 3)]);
            }
            #pragma unroll
            for (int mi = 0; mi < 2; ++mi) {
                int ar = wr * 32 + mi * 16 + (lane & 15);
                afr[mi] = *reinterpret_cast<const s16x8*>(
                    &Ar[ar * 72 + kk * 32 + kq * 8]);
            }
            #pragma unroll
            for (int mi = 0; mi < 2; ++mi)
                #pragma unroll
                for (int ni = 0; ni < 6; ++ni)
                    acc[mi][ni] = __builtin_amdgcn_mfma_f32_16x16x32_bf16(
                        afr[mi], bfr[ni], acc[mi][ni], 0, 0, 0);
        }
        if (t < 31) {
            s16x8 s = cvt8(gC[0], gC[1]);
            *reinterpret_cast<s16x8*>(&Af[(buf ^ 1) * ASZ + rowA * 72 + c8A * 8]) = s;
            if (t == 30) asm volatile("s_waitcnt vmcnt(0) lgkmcnt(0)" ::: "memory");
            else         asm volatile("s_waitcnt vmcnt(2) lgkmcnt(0)" ::: "memory");
            __builtin_amdgcn_s_barrier();
        }
    };
    for (int tt = 0; tt < 32; tt += 2) {
        body(tt,     ga, gb);
        body(tt + 1, gb, ga);
    }
    __syncthreads();   // phase-1 LDS reads complete; safe to overwrite with P

    // ---- transition: scale + cvt acc -> P_lds ----
    const int b = m0 >> 12;
    #pragma unroll
    for (int ni = 0; ni < 6; ++ni) {
        int col  = wc * 96 + ni * 16 + (lane & 15);
        float sc = scales[b * NATOMS + col / RANK];
        #pragma unroll
        for (int mi = 0; mi < 2; ++mi) {
            #pragma unroll
            for (int r = 0; r < 4; ++r) {
                int row = wr * 32 + mi * 16 + kq * 4 + r;
                Pl[row * PSTR + col] = f2bf(acc[mi][ni][r] * sc);
            }
        }
    }
    __syncthreads();

    // ---- phase 2 setup: 4-row x 2-col wave partition ----
    const int rw = w >> 1;      // 0..3: P-row group (16 rows)
    const int cw = w & 1;       // 0..1: col half of each 64-col tile

    // P fragments -> registers ONCE: 12 x s16x8 = 48 VGPRs, pinned.
    s16x8 pf[12];
    #pragma unroll
    for (int ks = 0; ks < 12; ++ks) {
        pf[ks] = *reinterpret_cast<const s16x8*>(
            &Pl[(rw * 16 + (lane & 15)) * PSTR + (ks * 4 + kq) * 8]);
        asm volatile("" : "+v"(pf[ks]));   // keep-alive: no LDS re-read
    }

    // Bt staging: 64 rows x 384 shorts = 3072 chunks of 16B; 6 gload_lds of
    // 8KB each.  Source pre-swizzled: LDS chunk c of row r holds global
    // chunk c^(r&7) -> read applies same XOR (involution).
    const unsigned short* srcB[6];
    int dstB[6];
    #pragma unroll
    for (int j = 0; j < 6; ++j) {
        int g  = j * 512 + tid;
        int rB = g / 48, cB = g % 48;
        srcB[j] = BbfT + (size_t)rB * NAR + (cB ^ (rB & 7)) * 8;
        dstB[j] = g * 8;   // linear LDS short offset
    }

    // prologue: stage Bt(0)
    #pragma unroll
    for (int j = 0; j < 6; ++j) gload_lds16(srcB[j], &Bt[dstB[j]]);
    asm volatile("s_waitcnt vmcnt(0)" ::: "memory");
    __builtin_amdgcn_s_barrier();

    // ---- phase 2 main loop: 32 p-tiles of 64 cols ----
    for (int pt = 0; pt < 32; ++pt) {
        const int buf = pt & 1;
        // 1. issue Bt(pt+1) gloads (oldest VMEM ops this tile)
        if (pt < 31) {
            #pragma unroll
            for (int j = 0; j < 6; ++j)
                gload_lds16(srcB[j] + (size_t)(pt + 1) * 64 * NAR,
                            &Bt[(buf ^ 1) * BSZ + dstB[j]]);
        }
        __builtin_amdgcn_sched_barrier(0);
        // 2. compute tile pt: wave covers rows rw*16..+16, cols cw*32..+32
        f32x4 a2[2] = {};
        const unsigned short* Br = &Bt[buf * BSZ];
        #pragma unroll
        for (int ks = 0; ks < 12; ++ks) {
            #pragma unroll
            for (int ni = 0; ni < 2; ++ni) {
                int rowB = cw * 32 + ni * 16 + (lane & 15);
                s16x8 bfr = *reinterpret_cast<const s16x8*>(
                    &Br[(rowB * 48 + ((ks * 4 + kq) ^ (rowB & 7))) * 8]);
                a2[ni] = __builtin_amdgcn_mfma_f32_16x16x32_bf16(
                    pf[ks], bfr, a2[ni], 0, 0, 0);
            }
        }
        // 3. store tile pt
        #pragma unroll
        for (int ni = 0; ni < 2; ++ni) {
            #pragma unroll
            for (int r = 0; r < 4; ++r) {
                int row = m0 + rw * 16 + kq * 4 + r;
                int col = pt * 64 + cw * 32 + ni * 16 + (lane & 15);
                out[(size_t)row * D_MODEL + col] = a2[ni][r];
            }
        }
        // 4. barrier: gloads (6 oldest) drained; this tile's stores in flight
        if (pt < 31) {
            asm volatile("s_waitcnt vmcnt(8)" ::: "memory");
            __builtin_amdgcn_s_barrier();
        }
    }
}

extern "C" void kernel_launch(void* const* d_in, const int* in_sizes, int n_in,
                              void* d_out, int out_size, void* d_ws, size_t ws_size,
                              hipStream_t stream)
{
    const float* hidden    = (const float*)d_in[0];
    const float* scales    = (const float*)d_in[1];
    const float* A         = (const float*)d_in[2];
    const float* B         = (const float*)d_in[3];
    const int*   layer_idx = (const int*)d_in[4];
    float* out = (float*)d_out;

    unsigned short* WbfT = (unsigned short*)d_ws;            // [384][2048]
    unsigned short* BbfT = WbfT + (size_t)NAR * D_MODEL;     // [2048][384]

    prep_kernel<<<(2 * NAR * D_MODEL) / 256, 256, 0, stream>>>(A, B, layer_idx, WbfT, BbfT);
    fused_lora<<<M_TOTAL / 64, 512, 0, stream>>>(hidden, scales, WbfT, BbfT, out);
}

// Round 15
// 90.755 us; speedup vs baseline: 1.1343x; 1.0484x over previous
//
#include <hip/hip_runtime.h>
#include <hip/hip_bf16.h>

typedef __attribute__((ext_vector_type(4))) float  f32x4;
typedef __attribute__((ext_vector_type(8))) short  s16x8;

#define D_MODEL 2048
#define NATOMS  64
#define RANK    6
#define NLAYERS 16
#define NAR     384
#define M_TOTAL 16384

#define ASZ  (64*72)    /* shorts: A buffer (+8 pad) */
#define WSZ  (384*64)   /* shorts: W buffer (linear, gload_lds) */
#define PSTR 392        /* P_lds row stride in shorts */
#define BSZ  (64*384)   /* shorts: one Bt buffer (linear, gload_lds) */

static __device__ __forceinline__ unsigned short f2bf(float x){
    union { float f; unsigned u; } v; v.f = x;
    unsigned r = (v.u + 0x7FFF + ((v.u >> 16) & 1)) >> 16;
    return (unsigned short)r;
}

static __device__ __forceinline__ void gload_lds16(const void* g, void* l) {
    __builtin_amdgcn_global_load_lds(
        (const __attribute__((address_space(1))) unsigned int*)g,
        (__attribute__((address_space(3))) unsigned int*)l, 16, 0, 0);
}

static __device__ __forceinline__ s16x8 cvt8(f32x4 lo, f32x4 hi) {
    union { s16x8 v; unsigned short s[8]; } u;
    u.s[0] = f2bf(lo.x); u.s[1] = f2bf(lo.y); u.s[2] = f2bf(lo.z); u.s[3] = f2bf(lo.w);
    u.s[4] = f2bf(hi.x); u.s[5] = f2bf(hi.y); u.s[6] = f2bf(hi.z); u.s[7] = f2bf(hi.w);
    return u.v;
}

// ---------------------------------------------------------------------------
// Prep: gather layer slice, cast to bf16, lay out K-contiguous.
//   WbfT[n][d]  (n = a*6+r)   from A[a, l, d, r]
//   BbfT[p][n]                from B[a, l, r, p]
// ---------------------------------------------------------------------------
__global__ void prep_kernel(const float* __restrict__ A,
                            const float* __restrict__ B,
                            const int*   __restrict__ layer_idx,
                            unsigned short* __restrict__ WbfT,
                            unsigned short* __restrict__ BbfT)
{
    const int l = layer_idx[0];
    int idx = blockIdx.x * 256 + threadIdx.x;
    const int total = NAR * D_MODEL;   // 786432
    if (idx < total) {
        int n = idx / D_MODEL, d = idx % D_MODEL;
        int a = n / RANK, r = n % RANK;
        float v = A[((size_t)(a*NLAYERS + l) * D_MODEL + d) * RANK + r];
        WbfT[idx] = f2bf(v);
    } else {
        idx -= total;
        int p = idx / NAR, n = idx % NAR;
        int a = n / RANK, r = n % RANK;
        float v = B[((size_t)(a*NLAYERS + l) * RANK + r) * D_MODEL + p];
        BbfT[idx] = f2bf(v);
    }
}

// ---------------------------------------------------------------------------
// Fused LoRA (256 blocks = 1/CU, 512 threads = 8 waves) — R10, best measured
// (88.2 µs timed).  Reverted here after R11-R14 refuted all further levers.
//   Phase 1: P[64][384] = scale*(hidden @ W^T) in regs; W dbuf gload_lds +
//            XOR swizzle; A reg-staged; counted vmcnt(2) barriers.
//   Phase 2: out[64][2048] = P @ B^T.  P via Pl (compiler re-reads; proven
//            non-binding by R12).  B staged per 64-col tile via gload_lds
//            dbuf (XOR-preswizzled source); tile barrier = vmcnt(8).
// ---------------------------------------------------------------------------
__global__ __launch_bounds__(512, 1) void fused_lora(
    const float*          __restrict__ hidden,  // [16384][2048] fp32
    const float*          __restrict__ scales,  // [4][64]
    const unsigned short* __restrict__ WbfT,    // [384][2048] bf16
    const unsigned short* __restrict__ BbfT,    // [2048][384] bf16
    float*                __restrict__ out)     // [16384][2048] fp32
{
    __shared__ __align__(16) char smem[148480];
    unsigned short* Af = (unsigned short*)smem;            // 2*ASZ  (18432 B)
    unsigned short* Wf = (unsigned short*)(smem + 18432);  // 2*WSZ  (98304 B)
    unsigned short* Pl = (unsigned short*)smem;            // 64x392 (50176 B)
    unsigned short* Bt = (unsigned short*)(smem + 50176);  // 2*BSZ  (98304 B)

    const int m0   = blockIdx.x * 64;
    const int tid  = threadIdx.x;
    const int lane = tid & 63;
    const int w    = tid >> 6;          // 0..7
    const int wr   = w >> 2, wc = w & 3;   // phase1: rows wr*32, cols wc*96
    const int kq   = lane >> 4;         // 0..3

    // ---- phase 1 setup ----
    const int rowA = tid >> 3;          // 0..63
    const int c8A  = tid & 7;           // 0..7
    const float* srcA = hidden + (size_t)(m0 + rowA) * D_MODEL + c8A * 8;

    // W staging: 48 gload_lds of 1KB; wave w does insts i = w*6+j.
    const unsigned short* srcW[6];
    int ldsW[6];
    #pragma unroll
    for (int j = 0; j < 6; ++j) {
        int i = w * 6 + j;
        int r = i * 8 + (lane >> 3);
        int c = (lane & 7) ^ (r & 7);
        srcW[j] = WbfT + (size_t)r * D_MODEL + c * 8;
        ldsW[j] = i * 512;   // shorts
    }

    f32x4 acc[2][6] = {};
    f32x4 ga[2], gb[2];

    // ---- phase 1 prologue ----
    ga[0] = *reinterpret_cast<const f32x4*>(srcA);
    ga[1] = *reinterpret_cast<const f32x4*>(srcA + 4);
    srcA += 64;
    {
        s16x8 s = cvt8(ga[0], ga[1]);
        *reinterpret_cast<s16x8*>(&Af[rowA * 72 + c8A * 8]) = s;
    }
    #pragma unroll
    for (int j = 0; j < 6; ++j) { gload_lds16(srcW[j], &Wf[ldsW[j]]); srcW[j] += 64; }
    __builtin_amdgcn_sched_barrier(0);
    gb[0] = *reinterpret_cast<const f32x4*>(srcA);          // A(1)
    gb[1] = *reinterpret_cast<const f32x4*>(srcA + 4);
    srcA += 64;
    asm volatile("s_waitcnt vmcnt(2) lgkmcnt(0)" ::: "memory");  // W(0) done, A(1) in flight
    __builtin_amdgcn_s_barrier();

    // ---- phase 1 main loop ----
    auto body = [&](int t, f32x4 (&gI)[2], f32x4 (&gC)[2]) {
        const int buf = t & 1;
        if (t < 31) {
            #pragma unroll
            for (int j = 0; j < 6; ++j) {
                gload_lds16(srcW[j], &Wf[(buf ^ 1) * WSZ + ldsW[j]]);
                srcW[j] += 64;
            }
        }
        __builtin_amdgcn_sched_barrier(0);   // pin: W gloads before A loads
        if (t < 30) {
            gI[0] = *reinterpret_cast<const f32x4*>(srcA);
            gI[1] = *reinterpret_cast<const f32x4*>(srcA + 4);
            srcA += 64;
        }
        const unsigned short* Ar = &Af[buf * ASZ];
        const unsigned short* Wr = &Wf[buf * WSZ];
        #pragma unroll
        for (int kk = 0; kk < 2; ++kk) {
            const int kch = kk * 4 + kq;
            s16x8 bfr[6], afr[2];
            #pragma unroll
            for (int ni = 0; ni < 6; ++ni) {
                int br = wc * 96 + ni * 16 + (lane & 15);
                bfr[ni] = *reinterpret_cast<const s16x8*>(
                    &Wr[br * 64 + ((kch ^ (br & 7)) << 3)]);
            }
            #pragma unroll
            for (int mi = 0; mi < 2; ++mi) {
                int ar = wr * 32 + mi * 16 + (lane & 15);
                afr[mi] = *reinterpret_cast<const s16x8*>(
                    &Ar[ar * 72 + kk * 32 + kq * 8]);
            }
            #pragma unroll
            for (int mi = 0; mi < 2; ++mi)
                #pragma unroll
                for (int ni = 0; ni < 6; ++ni)
                    acc[mi][ni] = __builtin_amdgcn_mfma_f32_16x16x32_bf16(
                        afr[mi], bfr[ni], acc[mi][ni], 0, 0, 0);
        }
        if (t < 31) {
            s16x8 s = cvt8(gC[0], gC[1]);
            *reinterpret_cast<s16x8*>(&Af[(buf ^ 1) * ASZ + rowA * 72 + c8A * 8]) = s;
            if (t == 30) asm volatile("s_waitcnt vmcnt(0) lgkmcnt(0)" ::: "memory");
            else         asm volatile("s_waitcnt vmcnt(2) lgkmcnt(0)" ::: "memory");
            __builtin_amdgcn_s_barrier();
        }
    };
    for (int tt = 0; tt < 32; tt += 2) {
        body(tt,     ga, gb);
        body(tt + 1, gb, ga);
    }
    __syncthreads();   // phase-1 LDS reads complete; safe to overwrite with P

    // ---- transition: scale + cvt acc -> P_lds ----
    const int b = m0 >> 12;
    #pragma unroll
    for (int ni = 0; ni < 6; ++ni) {
        int col  = wc * 96 + ni * 16 + (lane & 15);
        float sc = scales[b * NATOMS + col / RANK];
        #pragma unroll
        for (int mi = 0; mi < 2; ++mi) {
            #pragma unroll
            for (int r = 0; r < 4; ++r) {
                int row = wr * 32 + mi * 16 + kq * 4 + r;
                Pl[row * PSTR + col] = f2bf(acc[mi][ni][r] * sc);
            }
        }
    }
    __syncthreads();

    // ---- phase 2 setup ----
    const int wr2 = w >> 2, wp = w & 3;   // out rows wr2*32, cols pt*64 + wp*16

    // P fragments (compiler may re-read from Pl; proven non-binding by R12)
    s16x8 pf[2][12];
    #pragma unroll
    for (int mi = 0; mi < 2; ++mi)
        #pragma unroll
        for (int ks = 0; ks < 12; ++ks)
            pf[mi][ks] = *reinterpret_cast<const s16x8*>(
                &Pl[(wr2 * 32 + mi * 16 + (lane & 15)) * PSTR + (ks * 4 + kq) * 8]);

    // Bt staging: 64 rows x 384 shorts = 3072 chunks of 16B; 6 gload_lds of
    // 8KB each.  Source pre-swizzled: LDS chunk c of row r holds global
    // chunk c^(r&7) -> read applies same XOR (involution).
    const unsigned short* srcB[6];
    int dstB[6];
    #pragma unroll
    for (int j = 0; j < 6; ++j) {
        int g  = j * 512 + tid;
        int rB = g / 48, cB = g % 48;
        srcB[j] = BbfT + (size_t)rB * NAR + (cB ^ (rB & 7)) * 8;
        dstB[j] = g * 8;   // linear LDS short offset
    }
    const int rowB = wp * 16 + (lane & 15);

    // prologue: stage Bt(0)
    #pragma unroll
    for (int j = 0; j < 6; ++j) gload_lds16(srcB[j], &Bt[dstB[j]]);
    asm volatile("s_waitcnt vmcnt(0)" ::: "memory");
    __builtin_amdgcn_s_barrier();

    // ---- phase 2 main loop: 32 p-tiles of 64 cols ----
    for (int pt = 0; pt < 32; ++pt) {
        const int buf = pt & 1;
        // 1. issue Bt(pt+1) gloads (oldest VMEM ops this tile)
        if (pt < 31) {
            #pragma unroll
            for (int j = 0; j < 6; ++j)
                gload_lds16(srcB[j] + (size_t)(pt + 1) * 64 * NAR,
                            &Bt[(buf ^ 1) * BSZ + dstB[j]]);
        }
        __builtin_amdgcn_sched_barrier(0);
        // 2. compute tile pt from Bt[buf] + pf
        f32x4 a2[2] = {};
        const unsigned short* Br = &Bt[buf * BSZ];
        #pragma unroll
        for (int ks = 0; ks < 12; ++ks) {
            s16x8 bfr = *reinterpret_cast<const s16x8*>(
                &Br[(rowB * 48 + ((ks * 4 + kq) ^ (rowB & 7))) * 8]);
            #pragma unroll
            for (int mi = 0; mi < 2; ++mi)
                a2[mi] = __builtin_amdgcn_mfma_f32_16x16x32_bf16(
                    pf[mi][ks], bfr, a2[mi], 0, 0, 0);
        }
        // 3. store tile pt
        #pragma unroll
        for (int mi = 0; mi < 2; ++mi) {
            #pragma unroll
            for (int r = 0; r < 4; ++r) {
                int row = m0 + wr2 * 32 + mi * 16 + kq * 4 + r;
                int col = pt * 64 + wp * 16 + (lane & 15);
                out[(size_t)row * D_MODEL + col] = a2[mi][r];
            }
        }
        // 4. barrier: gloads (6 oldest) drained; this tile's stores in flight
        if (pt < 31) {
            asm volatile("s_waitcnt vmcnt(8)" ::: "memory");
            __builtin_amdgcn_s_barrier();
        }
    }
}

extern "C" void kernel_launch(void* const* d_in, const int* in_sizes, int n_in,
                              void* d_out, int out_size, void* d_ws, size_t ws_size,
                              hipStream_t stream)
{
    const float* hidden    = (const float*)d_in[0];
    const float* scales    = (const float*)d_in[1];
    const float* A         = (const float*)d_in[2];
    const float* B         = (const float*)d_in[3];
    const int*   layer_idx = (const int*)d_in[4];
    float* out = (float*)d_out;

    unsigned short* WbfT = (unsigned short*)d_ws;            // [384][2048]
    unsigned short* BbfT = WbfT + (size_t)NAR * D_MODEL;     // [2048][384]

    prep_kernel<<<(2 * NAR * D_MODEL) / 256, 256, 0, stream>>>(A, B, layer_idx, WbfT, BbfT);
    fused_lora<<<M_TOTAL / 64, 512, 0, stream>>>(hidden, scales, WbfT, BbfT, out);
}

// Round 16
// 87.413 us; speedup vs baseline: 1.1776x; 1.0382x over previous
//
#include <hip/hip_runtime.h>
#include <hip/hip_bf16.h>

typedef __attribute__((ext_vector_type(4))) float  f32x4;
typedef __attribute__((ext_vector_type(8))) short  s16x8;

#define D_MODEL 2048
#define NATOMS  64
#define RANK    6
#define NLAYERS 16
#define NAR     384
#define M_TOTAL 16384

#define ASZ  (64*72)    /* shorts: A buffer (+8 pad) */
#define WSZ  (384*64)   /* shorts: W buffer (linear, gload_lds) */
#define PSTR 392        /* P_lds row stride in shorts */
#define BSZ  (64*384)   /* shorts: one Bt buffer (linear, gload_lds) */

static __device__ __forceinline__ unsigned short f2bf(float x){
    union { float f; unsigned u; } v; v.f = x;
    unsigned r = (v.u + 0x7FFF + ((v.u >> 16) & 1)) >> 16;
    return (unsigned short)r;
}

static __device__ __forceinline__ void gload_lds16(const void* g, void* l) {
    __builtin_amdgcn_global_load_lds(
        (const __attribute__((address_space(1))) unsigned int*)g,
        (__attribute__((address_space(3))) unsigned int*)l, 16, 0, 0);
}

static __device__ __forceinline__ s16x8 cvt8(f32x4 lo, f32x4 hi) {
    union { s16x8 v; unsigned short s[8]; } u;
    u.s[0] = f2bf(lo.x); u.s[1] = f2bf(lo.y); u.s[2] = f2bf(lo.z); u.s[3] = f2bf(lo.w);
    u.s[4] = f2bf(hi.x); u.s[5] = f2bf(hi.y); u.s[6] = f2bf(hi.z); u.s[7] = f2bf(hi.w);
    return u.v;
}

// ---------------------------------------------------------------------------
// Prep: gather layer slice, cast to bf16, lay out K-contiguous.
// ---------------------------------------------------------------------------
__global__ void prep_kernel(const float* __restrict__ A,
                            const float* __restrict__ B,
                            const int*   __restrict__ layer_idx,
                            unsigned short* __restrict__ WbfT,
                            unsigned short* __restrict__ BbfT)
{
    const int l = layer_idx[0];
    int idx = blockIdx.x * 256 + threadIdx.x;
    const int total = NAR * D_MODEL;   // 786432
    if (idx < total) {
        int n = idx / D_MODEL, d = idx % D_MODEL;
        int a = n / RANK, r = n % RANK;
        float v = A[((size_t)(a*NLAYERS + l) * D_MODEL + d) * RANK + r];
        WbfT[idx] = f2bf(v);
    } else {
        idx -= total;
        int p = idx / NAR, n = idx % NAR;
        int a = n / RANK, r = n % RANK;
        float v = B[((size_t)(a*NLAYERS + l) * RANK + r) * D_MODEL + p];
        BbfT[idx] = f2bf(v);
    }
}

// ---------------------------------------------------------------------------
// Fused LoRA (256 blocks = 1/CU, 512 threads = 8 waves) — R10 structure with
// fine-grained issue interleave (T3-lite) + setprio (T5):
//   Phase 1 K-step split into two sub-phases:
//     [ds_read kk0 | 3 W gloads | MFMA x12] [ds_read kk1 | 3 W gloads +
//     A(t+2) | MFMA x12] [cvt + ds_write + vmcnt(2) barrier]
//   vmcnt arithmetic unchanged: 6 W gloads oldest, 2 A newest.
// ---------------------------------------------------------------------------
__global__ __launch_bounds__(512, 1) void fused_lora(
    const float*          __restrict__ hidden,  // [16384][2048] fp32
    const float*          __restrict__ scales,  // [4][64]
    const unsigned short* __restrict__ WbfT,    // [384][2048] bf16
    const unsigned short* __restrict__ BbfT,    // [2048][384] bf16
    float*                __restrict__ out)     // [16384][2048] fp32
{
    __shared__ __align__(16) char smem[148480];
    unsigned short* Af = (unsigned short*)smem;            // 2*ASZ  (18432 B)
    unsigned short* Wf = (unsigned short*)(smem + 18432);  // 2*WSZ  (98304 B)
    unsigned short* Pl = (unsigned short*)smem;            // 64x392 (50176 B)
    unsigned short* Bt = (unsigned short*)(smem + 50176);  // 2*BSZ  (98304 B)

    const int m0   = blockIdx.x * 64;
    const int tid  = threadIdx.x;
    const int lane = tid & 63;
    const int w    = tid >> 6;          // 0..7
    const int wr   = w >> 2, wc = w & 3;   // phase1: rows wr*32, cols wc*96
    const int kq   = lane >> 4;         // 0..3

    // ---- phase 1 setup ----
    const int rowA = tid >> 3;          // 0..63
    const int c8A  = tid & 7;           // 0..7
    const float* srcA = hidden + (size_t)(m0 + rowA) * D_MODEL + c8A * 8;

    // W staging: 48 gload_lds of 1KB; wave w does insts i = w*6+j.
    const unsigned short* srcW[6];
    int ldsW[6];
    #pragma unroll
    for (int j = 0; j < 6; ++j) {
        int i = w * 6 + j;
        int r = i * 8 + (lane >> 3);
        int c = (lane & 7) ^ (r & 7);
        srcW[j] = WbfT + (size_t)r * D_MODEL + c * 8;
        ldsW[j] = i * 512;   // shorts
    }

    f32x4 acc[2][6] = {};
    f32x4 ga[2], gb[2];

    // ---- phase 1 prologue ----
    ga[0] = *reinterpret_cast<const f32x4*>(srcA);
    ga[1] = *reinterpret_cast<const f32x4*>(srcA + 4);
    srcA += 64;
    {
        s16x8 s = cvt8(ga[0], ga[1]);
        *reinterpret_cast<s16x8*>(&Af[rowA * 72 + c8A * 8]) = s;
    }
    #pragma unroll
    for (int j = 0; j < 6; ++j) { gload_lds16(srcW[j], &Wf[ldsW[j]]); srcW[j] += 64; }
    __builtin_amdgcn_sched_barrier(0);
    gb[0] = *reinterpret_cast<const f32x4*>(srcA);          // A(1)
    gb[1] = *reinterpret_cast<const f32x4*>(srcA + 4);
    srcA += 64;
    asm volatile("s_waitcnt vmcnt(2) lgkmcnt(0)" ::: "memory");  // W(0) done, A(1) in flight
    __builtin_amdgcn_s_barrier();

    // ---- phase 1 main loop (two interleaved sub-phases per K-step) ----
    auto body = [&](int t, f32x4 (&gI)[2], f32x4 (&gC)[2]) {
        const int buf = t & 1;
        const unsigned short* Ar = &Af[buf * ASZ];
        const unsigned short* Wr = &Wf[buf * WSZ];

        // --- sub-phase 0: ds_read kk=0 frags ---
        s16x8 bfr0[6], afr0[2];
        {
            const int kch = kq;   // kk=0
            #pragma unroll
            for (int ni = 0; ni < 6; ++ni) {
                int br = wc * 96 + ni * 16 + (lane & 15);
                bfr0[ni] = *reinterpret_cast<const s16x8*>(
                    &Wr[br * 64 + ((kch ^ (br & 7)) << 3)]);
            }
            #pragma unroll
            for (int mi = 0; mi < 2; ++mi) {
                int ar = wr * 32 + mi * 16 + (lane & 15);
                afr0[mi] = *reinterpret_cast<const s16x8*>(&Ar[ar * 72 + kq * 8]);
            }
        }
        // issue first 3 W(t+1) gloads (oldest VMEM this iter)
        if (t < 31) {
            #pragma unroll
            for (int j = 0; j < 3; ++j) {
                gload_lds16(srcW[j], &Wf[(buf ^ 1) * WSZ + ldsW[j]]);
                srcW[j] += 64;
            }
        }
        __builtin_amdgcn_sched_barrier(0);
        // MFMA cluster 0
        __builtin_amdgcn_s_setprio(1);
        #pragma unroll
        for (int mi = 0; mi < 2; ++mi)
            #pragma unroll
            for (int ni = 0; ni < 6; ++ni)
                acc[mi][ni] = __builtin_amdgcn_mfma_f32_16x16x32_bf16(
                    afr0[mi], bfr0[ni], acc[mi][ni], 0, 0, 0);
        __builtin_amdgcn_s_setprio(0);
        __builtin_amdgcn_sched_barrier(0);

        // --- sub-phase 1: ds_read kk=1 frags ---
        s16x8 bfr1[6], afr1[2];
        {
            const int kch = 4 + kq;   // kk=1
            #pragma unroll
            for (int ni = 0; ni < 6; ++ni) {
                int br = wc * 96 + ni * 16 + (lane & 15);
                bfr1[ni] = *reinterpret_cast<const s16x8*>(
                    &Wr[br * 64 + ((kch ^ (br & 7)) << 3)]);
            }
            #pragma unroll
            for (int mi = 0; mi < 2; ++mi) {
                int ar = wr * 32 + mi * 16 + (lane & 15);
                afr1[mi] = *reinterpret_cast<const s16x8*>(
                    &Ar[ar * 72 + 32 + kq * 8]);
            }
        }
        // issue remaining 3 W(t+1) gloads, then A(t+2) (newest VMEM)
        if (t < 31) {
            #pragma unroll
            for (int j = 3; j < 6; ++j) {
                gload_lds16(srcW[j], &Wf[(buf ^ 1) * WSZ + ldsW[j]]);
                srcW[j] += 64;
            }
        }
        __builtin_amdgcn_sched_barrier(0);   // pin: W gloads before A loads
        if (t < 30) {
            gI[0] = *reinterpret_cast<const f32x4*>(srcA);
            gI[1] = *reinterpret_cast<const f32x4*>(srcA + 4);
            srcA += 64;
        }
        __builtin_amdgcn_sched_barrier(0);
        // MFMA cluster 1
        __builtin_amdgcn_s_setprio(1);
        #pragma unroll
        for (int mi = 0; mi < 2; ++mi)
            #pragma unroll
            for (int ni = 0; ni < 6; ++ni)
                acc[mi][ni] = __builtin_amdgcn_mfma_f32_16x16x32_bf16(
                    afr1[mi], bfr1[ni], acc[mi][ni], 0, 0, 0);
        __builtin_amdgcn_s_setprio(0);

        // --- tail: cvt A(t+1) -> LDS, counted-vmcnt barrier ---
        if (t < 31) {
            s16x8 s = cvt8(gC[0], gC[1]);
            *reinterpret_cast<s16x8*>(&Af[(buf ^ 1) * ASZ + rowA * 72 + c8A * 8]) = s;
            if (t == 30) asm volatile("s_waitcnt vmcnt(0) lgkmcnt(0)" ::: "memory");
            else         asm volatile("s_waitcnt vmcnt(2) lgkmcnt(0)" ::: "memory");
            __builtin_amdgcn_s_barrier();
        }
    };
    for (int tt = 0; tt < 32; tt += 2) {
        body(tt,     ga, gb);
        body(tt + 1, gb, ga);
    }
    __syncthreads();   // phase-1 LDS reads complete; safe to overwrite with P

    // ---- transition: scale + cvt acc -> P_lds ----
    const int b = m0 >> 12;
    #pragma unroll
    for (int ni = 0; ni < 6; ++ni) {
        int col  = wc * 96 + ni * 16 + (lane & 15);
        float sc = scales[b * NATOMS + col / RANK];
        #pragma unroll
        for (int mi = 0; mi < 2; ++mi) {
            #pragma unroll
            for (int r = 0; r < 4; ++r) {
                int row = wr * 32 + mi * 16 + kq * 4 + r;
                Pl[row * PSTR + col] = f2bf(acc[mi][ni][r] * sc);
            }
        }
    }
    __syncthreads();

    // ---- phase 2 setup ----
    const int wr2 = w >> 2, wp = w & 3;   // out rows wr2*32, cols pt*64 + wp*16

    s16x8 pf[2][12];
    #pragma unroll
    for (int mi = 0; mi < 2; ++mi)
        #pragma unroll
        for (int ks = 0; ks < 12; ++ks)
            pf[mi][ks] = *reinterpret_cast<const s16x8*>(
                &Pl[(wr2 * 32 + mi * 16 + (lane & 15)) * PSTR + (ks * 4 + kq) * 8]);

    // Bt staging: 3072 chunks of 16B; 6 gload_lds of 8KB each; source
    // pre-swizzled: LDS chunk c of row r holds global chunk c^(r&7).
    const unsigned short* srcB[6];
    int dstB[6];
    #pragma unroll
    for (int j = 0; j < 6; ++j) {
        int g  = j * 512 + tid;
        int rB = g / 48, cB = g % 48;
        srcB[j] = BbfT + (size_t)rB * NAR + (cB ^ (rB & 7)) * 8;
        dstB[j] = g * 8;   // linear LDS short offset
    }
    const int rowB = wp * 16 + (lane & 15);

    // prologue: stage Bt(0)
    #pragma unroll
    for (int j = 0; j < 6; ++j) gload_lds16(srcB[j], &Bt[dstB[j]]);
    asm volatile("s_waitcnt vmcnt(0)" ::: "memory");
    __builtin_amdgcn_s_barrier();

    // ---- phase 2 main loop: 32 p-tiles of 64 cols ----
    for (int pt = 0; pt < 32; ++pt) {
        const int buf = pt & 1;
        if (pt < 31) {
            #pragma unroll
            for (int j = 0; j < 6; ++j)
                gload_lds16(srcB[j] + (size_t)(pt + 1) * 64 * NAR,
                            &Bt[(buf ^ 1) * BSZ + dstB[j]]);
        }
        __builtin_amdgcn_sched_barrier(0);
        f32x4 a2[2] = {};
        const unsigned short* Br = &Bt[buf * BSZ];
        __builtin_amdgcn_s_setprio(1);
        #pragma unroll
        for (int ks = 0; ks < 12; ++ks) {
            s16x8 bfr = *reinterpret_cast<const s16x8*>(
                &Br[(rowB * 48 + ((ks * 4 + kq) ^ (rowB & 7))) * 8]);
            #pragma unroll
            for (int mi = 0; mi < 2; ++mi)
                a2[mi] = __builtin_amdgcn_mfma_f32_16x16x32_bf16(
                    pf[mi][ks], bfr, a2[mi], 0, 0, 0);
        }
        __builtin_amdgcn_s_setprio(0);
        #pragma unroll
        for (int mi = 0; mi < 2; ++mi) {
            #pragma unroll
            for (int r = 0; r < 4; ++r) {
                int row = m0 + wr2 * 32 + mi * 16 + kq * 4 + r;
                int col = pt * 64 + wp * 16 + (lane & 15);
                out[(size_t)row * D_MODEL + col] = a2[mi][r];
            }
        }
        if (pt < 31) {
            asm volatile("s_waitcnt vmcnt(8)" ::: "memory");
            __builtin_amdgcn_s_barrier();
        }
    }
}

extern "C" void kernel_launch(void* const* d_in, const int* in_sizes, int n_in,
                              void* d_out, int out_size, void* d_ws, size_t ws_size,
                              hipStream_t stream)
{
    const float* hidden    = (const float*)d_in[0];
    const float* scales    = (const float*)d_in[1];
    const float* A         = (const float*)d_in[2];
    const float* B         = (const float*)d_in[3];
    const int*   layer_idx = (const int*)d_in[4];
    float* out = (float*)d_out;

    unsigned short* WbfT = (unsigned short*)d_ws;            // [384][2048]
    unsigned short* BbfT = WbfT + (size_t)NAR * D_MODEL;     // [2048][384]

    prep_kernel<<<(2 * NAR * D_MODEL) / 256, 256, 0, stream>>>(A, B, layer_idx, WbfT, BbfT);
    fused_lora<<<M_TOTAL / 64, 512, 0, stream>>>(hidden, scales, WbfT, BbfT, out);
}